// Round 13
// baseline (99.244 us; speedup 1.0000x reference)
//
#include <hip/hip_runtime.h>
#include <math.h>

// LMAX=3, NMAX=3, RC=6, UNIT=1.0, NSPEC=4, L=4
// c[s][n][a][b]: 256 floats; per-species comp k = n*16 + a*4 + b (64 comps)
// *** DIAGNOSTIC ROUND: inner loop swept TWICE (+ exact x0.5 rescale) to push
// *** soap_accum above the ~43us fillBuffer wall so its counters show in top-5.
constexpr int   NB   = 1024;          // accum blocks
constexpr int   BT   = 256;           // 4 waves per block; wave id == species
constexpr int   NREP = 8;             // c_glob replicas
constexpr float RC   = 6.0f;

__device__ inline void global_fadd(float* p, float v) {
    unsafeAtomicAdd(p, v);            // HW global_atomic_add_f32, no return
}

// ---------------- kernel 0: zero the replicated global accumulator --------
__global__ __launch_bounds__(256) void soap_zero(float* __restrict__ c) {
    c[blockIdx.x * 256 + threadIdx.x] = 0.0f;      // <<<NREP, 256>>>
}

// per-atom feature accumulation (fully inlined, compile-time indices)
__device__ __forceinline__ void soap_atom(float* acc, float x, float y, float z,
                                          float f0_masked) {
    const float r2 = x * x + y * y + z * z;
    const float f0 = f0_masked;
    const float f1 = f0 * r2;
    const float f2 = f1 * r2;
    const float f3 = f2 * r2;

    #define ACC4(q, val) do { const float yv_ = (val);          \
        acc[(q)]      = fmaf(f0, yv_, acc[(q)]);                \
        acc[16 + (q)] = fmaf(f1, yv_, acc[16 + (q)]);           \
        acc[32 + (q)] = fmaf(f2, yv_, acc[32 + (q)]);           \
        acc[48 + (q)] = fmaf(f3, yv_, acc[48 + (q)]); } while (0)

    // l = 0 : Y = 1
    acc[0] += f0; acc[16] += f1; acc[32] += f2; acc[48] += f3;
    // l = 1
    const float Re11 = 0.5f * x, Im11 = 0.5f * y, Re10 = z;
    ACC4(5, Re10); ACC4(4, Re11); ACC4(1, Im11);
    // l = 2
    const float Re22 = 0.25f * (x * Re11 - y * Im11);
    const float Im22 = 0.25f * (x * Im11 + y * Re11);
    const float Re21 = z * Re11, Im21 = z * Im11;
    const float Re20 = 0.25f * (3.0f * z * Re10 - r2);
    ACC4(10, Re20); ACC4(9, Re21); ACC4(6, Im21); ACC4(8, Re22); ACC4(2, Im22);
    // l = 3
    const float Re33 = (x * Re22 - y * Im22) * (1.0f / 6.0f);
    const float Im33 = (x * Im22 + y * Re22) * (1.0f / 6.0f);
    const float Re32 = z * Re22, Im32 = z * Im22;
    const float Re30 = (5.0f * z * Re20 - r2 * Re10) * (1.0f / 9.0f);
    const float Re31 = (5.0f * z * Re21 - r2 * Re11) * (1.0f / 8.0f);
    const float Im31 = (5.0f * z * Im21 - r2 * Im11) * (1.0f / 8.0f);
    ACC4(15, Re30); ACC4(14, Re31); ACC4(11, Im31); ACC4(13, Re32);
    ACC4(7, Im32); ACC4(12, Re33); ACC4(3, Im33);
    #undef ACC4
}

// radial*cutoff*species mask for one atom
__device__ __forceinline__ float soap_f0(float x, float y, float z,
                                         int s, int ws, bool valid) {
    const float r2 = x * x + y * y + z * z;
    const float dd = sqrtf(r2);
    const float t  = fmaxf(1.0f - dd * (1.0f / RC), 0.0f);
    float f0 = __expf(-0.5f * r2) * t * t;
    return (s == ws && valid) ? f0 : 0.0f;
}

// ---------------- kernel 1: 4 atoms/lane/iter, vectorized loads ------------
__global__ __launch_bounds__(BT, 3) void soap_accum(const float* __restrict__ coo,
                                                    const int*   __restrict__ numbers,
                                                    float*       __restrict__ c_glob,
                                                    int n) {
    const int lane = threadIdx.x & 63;
    const int ws   = threadIdx.x >> 6;             // wave id == species (0..3)
    const int nb4  = n >> 2;                       // 4-atom batches
    const int bstride = NB * 64;                   // batches per grid sweep

    const float4* __restrict__ coo4 = (const float4*)coo;
    const int4*   __restrict__ num4 = (const int4*)numbers;

    float acc[64];
    #pragma unroll
    for (int k = 0; k < 64; ++k) acc[k] = 0.0f;

    // DIAGNOSTIC: two identical sweeps, rescaled by exact 0.5 below.
    #pragma unroll 1
    for (int sweep = 0; sweep < 2; ++sweep) {
        int b = blockIdx.x * 64 + lane;
        int jb = (b < nb4) ? b : (nb4 - 1);        // clamped load index
        float4 A = coo4[3 * jb + 0];
        float4 B = coo4[3 * jb + 1];
        float4 C = coo4[3 * jb + 2];
        int4   S = num4[jb];

        while (b < nb4) {
            const int bn  = b + bstride;
            const int jbn = (bn < nb4) ? bn : (nb4 - 1);
            const float4 An = coo4[3 * jbn + 0];
            const float4 Bn = coo4[3 * jbn + 1];
            const float4 Cn = coo4[3 * jbn + 2];
            const int4   Sn = num4[jbn];

            const int a0 = 4 * b;                  // this lane's first atom index
            soap_atom(acc, A.x, A.y, A.z, soap_f0(A.x, A.y, A.z, S.x, ws, a0 + 0 < n));
            soap_atom(acc, A.w, B.x, B.y, soap_f0(A.w, B.x, B.y, S.y, ws, a0 + 1 < n));
            soap_atom(acc, B.z, B.w, C.x, soap_f0(B.z, B.w, C.x, S.z, ws, a0 + 2 < n));
            soap_atom(acc, C.y, C.z, C.w, soap_f0(C.y, C.z, C.w, S.w, ws, a0 + 3 < n));

            A = An; B = Bn; C = Cn; S = Sn;
            b = bn;
        }
    }
    #pragma unroll
    for (int k = 0; k < 64; ++k) acc[k] *= 0.5f;   // undo the double count (exact)

    // ---- in-register wave reduction: bisection over lanes ----
    // After 6 stages, lane k holds the wave-total of component k.
    #pragma unroll
    for (int m = 32; m >= 1; m >>= 1) {
        const bool hi = (lane & m) != 0;
        #pragma unroll
        for (int q = 0; q < m; ++q) {
            const float give = hi ? acc[q] : acc[q + m];
            const float keep = hi ? acc[q + m] : acc[q];
            acc[q] = keep + __shfl_xor(give, m, 64);
        }
    }
    // one atomic per thread into this block's replica
    global_fadd(&c_glob[(blockIdx.x & (NREP - 1)) * 256 + ws * 64 + lane], acc[0]);
}

// ---------------- kernel 2: bilinear contraction + normalize ---------------
__global__ __launch_bounds__(1024) void soap_finish(const float* __restrict__ c_glob,
                                                    float* __restrict__ out) {
    __shared__ float c[256];
    __shared__ float red[16];
    __shared__ float snorm;
    const int t = threadIdx.x;
    if (t < 256) {
        float s = 0.0f;
        #pragma unroll
        for (int rep = 0; rep < NREP; ++rep) s += c_glob[rep * 256 + t];
        c[t] = s;
    }
    __syncthreads();

    // p index (i,j,k,n,x), t = i*256 + j*64 + k*16 + n*4 + x
    const int x  = t & 3;
    const int nn = (t >> 2) & 3;
    const int kk = (t >> 4) & 3;
    const int j  = (t >> 6) & 3;
    const int i  = (t >> 8) & 3;

    float p1 = 0.0f, p2 = 0.0f;
    #pragma unroll
    for (int b = 0; b < 4; ++b) {
        const float yr = (x > b) ? 2.0f : ((x == b) ? 1.0f : 0.0f);
        p1 += yr * c[((j * 4 + nn) * 4 + x) * 4 + b] * c[((i * 4 + kk) * 4 + x) * 4 + b];
    }
    #pragma unroll
    for (int a = 0; a < 4; ++a) {
        const float yi = (x > a) ? 2.0f : 0.0f;
        p2 += yi * c[((j * 4 + nn) * 4 + a) * 4 + x] * c[((i * 4 + kk) * 4 + a) * 4 + x];
    }

    const double fact[8] = {1, 1, 2, 6, 24, 120, 720, 5040};
    const double ak = 1.0 / ((2 * x + 1) * exp2((double)(2 * kk + x)) * fact[kk] * fact[kk + x]);
    const double an = 1.0 / ((2 * x + 1) * exp2((double)(2 * nn + x)) * fact[nn] * fact[nn + x]);
    const float val = (p1 + p2) * (float)sqrt(ak * an);

    float sq = val * val;
    #pragma unroll
    for (int off = 32; off > 0; off >>= 1) sq += __shfl_down(sq, off, 64);
    if ((t & 63) == 0) red[t >> 6] = sq;
    __syncthreads();
    if (t == 0) {
        float ssum = 0.0f;
        #pragma unroll
        for (int w = 0; w < 16; ++w) ssum += red[w];
        snorm = sqrtf(ssum);
    }
    __syncthreads();

    out[t] = val / (snorm + 1.1920929e-07f);
}

// ---------------- launch ----------------
extern "C" void kernel_launch(void* const* d_in, const int* in_sizes, int n_in,
                              void* d_out, int out_size, void* d_ws, size_t ws_size,
                              hipStream_t stream) {
    const float* coo     = (const float*)d_in[0];
    const int*   numbers = (const int*)d_in[1];
    const int    n       = in_sizes[1];
    float*       c_glob  = (float*)d_ws;     // NREP*256 floats
    float*       out     = (float*)d_out;

    soap_zero  <<<NREP, 256, 0, stream>>>(c_glob);
    soap_accum <<<NB,   BT,  0, stream>>>(coo, numbers, c_glob, n);
    soap_finish<<<1,   1024, 0, stream>>>(c_glob, out);
}

// Round 15
// 78.861 us; speedup vs baseline: 1.2585x; 1.2585x over previous
//
#include <hip/hip_runtime.h>
#include <math.h>

// LMAX=3, NMAX=3, RC=6, UNIT=1.0, NSPEC=4, L=4
// c[s][n][a][b]: 256 floats; per-species comp k = n*16 + a*4 + b (64 comps)
// R15 = R14 (LDS species-binning, each atom computed once) + NaN fix:
// invalid tail lanes must get ZERO COORDS, not just zero f0 (0*inf=NaN from
// uninitialized LDS garbage read through the clamped index).
constexpr int   BT   = 256;           // 4 waves per block; wave w consumes species w
constexpr int   TILE = 1024;          // atoms per block (4 per thread)
constexpr int   CAP  = 160;           // per-wave per-species bin capacity (14 sigma)
constexpr int   NREP = 8;             // c_glob replicas
constexpr float RC   = 6.0f;

__device__ inline void global_fadd(float* p, float v) {
    unsafeAtomicAdd(p, v);            // HW global_atomic_add_f32, no return
}

// ---------------- kernel 0: zero the replicated global accumulator --------
__global__ __launch_bounds__(256) void soap_zero(float* __restrict__ c) {
    c[blockIdx.x * 256 + threadIdx.x] = 0.0f;      // <<<NREP, 256>>>
}

// per-atom feature accumulation (fully inlined, compile-time indices)
__device__ __forceinline__ void soap_atom(float* acc, float x, float y, float z,
                                          float f0) {
    const float r2 = x * x + y * y + z * z;
    const float f1 = f0 * r2;
    const float f2 = f1 * r2;
    const float f3 = f2 * r2;

    #define ACC4(q, val) do { const float yv_ = (val);          \
        acc[(q)]      = fmaf(f0, yv_, acc[(q)]);                \
        acc[16 + (q)] = fmaf(f1, yv_, acc[16 + (q)]);           \
        acc[32 + (q)] = fmaf(f2, yv_, acc[32 + (q)]);           \
        acc[48 + (q)] = fmaf(f3, yv_, acc[48 + (q)]); } while (0)

    // l = 0 : Y = 1
    acc[0] += f0; acc[16] += f1; acc[32] += f2; acc[48] += f3;
    // l = 1
    const float Re11 = 0.5f * x, Im11 = 0.5f * y, Re10 = z;
    ACC4(5, Re10); ACC4(4, Re11); ACC4(1, Im11);
    // l = 2
    const float Re22 = 0.25f * (x * Re11 - y * Im11);
    const float Im22 = 0.25f * (x * Im11 + y * Re11);
    const float Re21 = z * Re11, Im21 = z * Im11;
    const float Re20 = 0.25f * (3.0f * z * Re10 - r2);
    ACC4(10, Re20); ACC4(9, Re21); ACC4(6, Im21); ACC4(8, Re22); ACC4(2, Im22);
    // l = 3
    const float Re33 = (x * Re22 - y * Im22) * (1.0f / 6.0f);
    const float Im33 = (x * Im22 + y * Re22) * (1.0f / 6.0f);
    const float Re32 = z * Re22, Im32 = z * Im22;
    const float Re30 = (5.0f * z * Re20 - r2 * Re10) * (1.0f / 9.0f);
    const float Re31 = (5.0f * z * Re21 - r2 * Re11) * (1.0f / 8.0f);
    const float Im31 = (5.0f * z * Im21 - r2 * Im11) * (1.0f / 8.0f);
    ACC4(15, Re30); ACC4(14, Re31); ACC4(11, Im31); ACC4(13, Re32);
    ACC4(7, Im32); ACC4(12, Re33); ACC4(3, Im33);
    #undef ACC4
}

__device__ __forceinline__ float soap_radial(float x, float y, float z) {
    const float r2 = x * x + y * y + z * z;
    const float dd = sqrtf(r2);
    const float t  = fmaxf(1.0f - dd * (1.0f / RC), 0.0f);
    return __expf(-0.5f * r2) * t * t;
}

// ---------------- kernel 1: bin by species in LDS, compute once -----------
__global__ __launch_bounds__(BT, 3) void soap_accum(const float* __restrict__ coo,
                                                    const int*   __restrict__ numbers,
                                                    float*       __restrict__ c_glob,
                                                    int n) {
    __shared__ float4 bins[4][4][CAP];             // [writer wave][species][slot]
    __shared__ int    cnts[4][4];                  // [writer wave][species]
    __shared__ unsigned long long ovf[4][4];       // [writer wave][slot] overflow lanes

    const int lane = threadIdx.x & 63;
    const int w    = threadIdx.x >> 6;             // wave id; phase2: species = w
    const int nb4  = n >> 2;                       // full 4-atom quads (n = 1M: exact)

    const float4* __restrict__ coo4 = (const float4*)coo;
    const int4*   __restrict__ num4 = (const int4*)numbers;

    // ---- load this thread's 4 atoms (48B contiguous) ----
    const int q  = (blockIdx.x * TILE >> 2) + threadIdx.x;   // quad index
    const int jq = (q < nb4) ? q : (nb4 - 1);                // clamped
    const float4 A = coo4[3 * jq + 0];
    const float4 B = coo4[3 * jq + 1];
    const float4 C = coo4[3 * jq + 2];
    const int4   S = num4[jq];
    const bool   qv = (q < nb4);                   // n%4==0 -> per-quad validity

    const float ax[4] = {A.x, A.w, B.z, C.y};
    const float ay[4] = {A.y, B.x, B.w, C.z};
    const float az[4] = {A.z, B.y, C.x, C.w};
    const int   as[4] = {S.x, S.y, S.z, S.w};

    // ---- phase 1: wave-private scatter into species bins (no atomics) ----
    int cur0 = 0, cur1 = 0, cur2 = 0, cur3 = 0;
    const unsigned long long below = (1ull << lane) - 1ull;
    #pragma unroll
    for (int slot = 0; slot < 4; ++slot) {
        unsigned long long ov = 0;
        #pragma unroll
        for (int sp = 0; sp < 4; ++sp) {
            int& cur = (sp == 0) ? cur0 : (sp == 1) ? cur1 : (sp == 2) ? cur2 : cur3;
            const bool m = qv && (as[slot] == sp);
            const unsigned long long bal = __ballot(m);
            const int pos = cur + __popcll(bal & below);
            if (m && pos < CAP)
                bins[w][sp][pos] = make_float4(ax[slot], ay[slot], az[slot], 0.0f);
            ov |= __ballot(m && pos >= CAP);
            cur += __popcll(bal);
        }
        if (lane == 0) ovf[w][slot] = ov;
    }
    if (lane == 0) {
        cnts[w][0] = (cur0 < CAP) ? cur0 : CAP;
        cnts[w][1] = (cur1 < CAP) ? cur1 : CAP;
        cnts[w][2] = (cur2 < CAP) ? cur2 : CAP;
        cnts[w][3] = (cur3 < CAP) ? cur3 : CAP;
    }
    __syncthreads();

    // ---- phase 2: wave w consumes species-w entries from all 4 segments ----
    float acc[64];
    #pragma unroll
    for (int k = 0; k < 64; ++k) acc[k] = 0.0f;

    #pragma unroll
    for (int seg = 0; seg < 4; ++seg) {
        const int c = cnts[seg][w];
        #pragma unroll 1
        for (int base = 0; base < c; base += 64) {
            const int  idx   = base + lane;
            const int  ridx  = (idx < CAP) ? idx : (CAP - 1);  // clamp LDS read
            const float4 v   = bins[seg][w][ridx];
            const bool valid = (idx < c);
            // NaN fix: invalid lanes get ZERO COORDS (garbage coords * f0=0
            // can be 0*inf=NaN). With (0,0,0): r2=0, all terms exactly 0.
            const float vx = valid ? v.x : 0.0f;
            const float vy = valid ? v.y : 0.0f;
            const float vz = valid ? v.z : 0.0f;
            const float f0 = valid ? soap_radial(vx, vy, vz) : 0.0f;
            soap_atom(acc, vx, vy, vz, f0);
        }
    }

    // ---- overflow fixup (probability ~1e-40; correctness safety net) ----
    unsigned long long anyov = 0;
    #pragma unroll
    for (int w2 = 0; w2 < 4; ++w2)
        #pragma unroll
        for (int slot = 0; slot < 4; ++slot) anyov |= ovf[w2][slot];
    if (anyov != 0ull) {
        for (int w2 = 0; w2 < 4; ++w2)
            for (int slot = 0; slot < 4; ++slot) {
                unsigned long long m = ovf[w2][slot];
                while (m != 0ull) {
                    const int b = __builtin_ctzll(m);
                    m &= m - 1ull;
                    const int atom = 4 * ((blockIdx.x * TILE >> 2) + w2 * 64 + b) + slot;
                    const float x = coo[3 * atom + 0];
                    const float y = coo[3 * atom + 1];
                    const float z = coo[3 * atom + 2];
                    const int   s = numbers[atom];
                    const bool  use = (s == w && lane == 0);   // count once
                    const float xx = use ? x : 0.0f;
                    const float yy = use ? y : 0.0f;
                    const float zz = use ? z : 0.0f;
                    const float f0 = use ? soap_radial(xx, yy, zz) : 0.0f;
                    soap_atom(acc, xx, yy, zz, f0);
                }
            }
    }

    // ---- in-register wave reduction: bisection over lanes ----
    // After 6 stages, lane k holds the wave-total of component k.
    #pragma unroll
    for (int m = 32; m >= 1; m >>= 1) {
        const bool hi = (lane & m) != 0;
        #pragma unroll
        for (int qq = 0; qq < m; ++qq) {
            const float give = hi ? acc[qq] : acc[qq + m];
            const float keep = hi ? acc[qq + m] : acc[qq];
            acc[qq] = keep + __shfl_xor(give, m, 64);
        }
    }
    // one atomic per thread into this block's replica; wave w == species w
    global_fadd(&c_glob[(blockIdx.x & (NREP - 1)) * 256 + w * 64 + lane], acc[0]);
}

// ---------------- kernel 2: bilinear contraction + normalize ---------------
__global__ __launch_bounds__(1024) void soap_finish(const float* __restrict__ c_glob,
                                                    float* __restrict__ out) {
    __shared__ float c[256];
    __shared__ float red[16];
    __shared__ float snorm;
    const int t = threadIdx.x;
    if (t < 256) {
        float s = 0.0f;
        #pragma unroll
        for (int rep = 0; rep < NREP; ++rep) s += c_glob[rep * 256 + t];
        c[t] = s;
    }
    __syncthreads();

    // p index (i,j,k,n,x), t = i*256 + j*64 + k*16 + n*4 + x
    const int x  = t & 3;
    const int nn = (t >> 2) & 3;
    const int kk = (t >> 4) & 3;
    const int j  = (t >> 6) & 3;
    const int i  = (t >> 8) & 3;

    float p1 = 0.0f, p2 = 0.0f;
    #pragma unroll
    for (int b = 0; b < 4; ++b) {
        const float yr = (x > b) ? 2.0f : ((x == b) ? 1.0f : 0.0f);
        p1 += yr * c[((j * 4 + nn) * 4 + x) * 4 + b] * c[((i * 4 + kk) * 4 + x) * 4 + b];
    }
    #pragma unroll
    for (int a = 0; a < 4; ++a) {
        const float yi = (x > a) ? 2.0f : 0.0f;
        p2 += yi * c[((j * 4 + nn) * 4 + a) * 4 + x] * c[((i * 4 + kk) * 4 + a) * 4 + x];
    }

    const double fact[8] = {1, 1, 2, 6, 24, 120, 720, 5040};
    const double ak = 1.0 / ((2 * x + 1) * exp2((double)(2 * kk + x)) * fact[kk] * fact[kk + x]);
    const double an = 1.0 / ((2 * x + 1) * exp2((double)(2 * nn + x)) * fact[nn] * fact[nn + x]);
    const float val = (p1 + p2) * (float)sqrt(ak * an);

    float sq = val * val;
    #pragma unroll
    for (int off = 32; off > 0; off >>= 1) sq += __shfl_down(sq, off, 64);
    if ((t & 63) == 0) red[t >> 6] = sq;
    __syncthreads();
    if (t == 0) {
        float ssum = 0.0f;
        #pragma unroll
        for (int ww = 0; ww < 16; ++ww) ssum += red[ww];
        snorm = sqrtf(ssum);
    }
    __syncthreads();

    out[t] = val / (snorm + 1.1920929e-07f);
}

// ---------------- launch ----------------
extern "C" void kernel_launch(void* const* d_in, const int* in_sizes, int n_in,
                              void* d_out, int out_size, void* d_ws, size_t ws_size,
                              hipStream_t stream) {
    const float* coo     = (const float*)d_in[0];
    const int*   numbers = (const int*)d_in[1];
    const int    n       = in_sizes[1];
    float*       c_glob  = (float*)d_ws;     // NREP*256 floats
    float*       out     = (float*)d_out;

    const int nblocks = (n + TILE - 1) / TILE;   // 977 for n = 1e6

    soap_zero  <<<NREP,    256, 0, stream>>>(c_glob);
    soap_accum <<<nblocks, BT,  0, stream>>>(coo, numbers, c_glob, n);
    soap_finish<<<1,      1024, 0, stream>>>(c_glob, out);
}